// Round 2
// baseline (290.465 us; speedup 1.0000x reference)
//
#include <hip/hip_runtime.h>
#include <hip/hip_bf16.h>

#define DIN    4096
#define DOUT   11008
#define TM     64
#define KSPLIT 8
#define KCHUNK (DIN / KSPLIT)     // 512
#define NCHUNKS (DOUT / 16)       // 688

typedef __attribute__((ext_vector_type(8))) short  bf16x8;
typedef __attribute__((ext_vector_type(4))) float  f32x4;

// floor(log2(safe_amax)) - 2, clipped; scale and 1/scale are powers of 2 (exact)
__device__ inline void mx_block_scale(float amax, float& scale, float& inv_scale) {
    float safe = amax > 0.0f ? amax : 1.0f;
    int e  = (int)((__float_as_uint(safe) >> 23) & 255) - 127; // floor(log2), normals
    int se = e - 2;
    if (se < -127) se = -127;       // E8M0_MIN clip (upper clip unreachable)
    scale     = ldexpf(1.0f, se);
    inv_scale = ldexpf(1.0f, -se);
}

// E2M1 quant-dequant of one element given the block scale (exact vs jnp ref)
__device__ inline float mx_qd(float v, float scale, float inv_scale) {
    float a = fabsf(v) * inv_scale;  // exact pow2 mult
    a = fminf(a, 6.0f);              // FP4_MAX saturate
    float step  = (a < 2.0f) ? 0.5f : (a < 4.0f) ? 1.0f : 2.0f;
    float rstep = (a < 2.0f) ? 2.0f : (a < 4.0f) ? 1.0f : 0.5f;
    float q = rintf(a * rstep) * step;   // round-half-even = jnp.round
    return copysignf(q * scale, v);
}

__device__ inline short bf16_trunc(float f) {
    // dequantized values have <=2 mantissa bits -> truncation exact
    return (short)(__float_as_uint(f) >> 16);
}

// ---------------- kernel 1: quantize x -> bf16 in ws (exact) ----------------
__global__ __launch_bounds__(256) void quant_x_kernel(const float* __restrict__ x,
                                                      unsigned short* __restrict__ x_dq) {
    int gid = blockIdx.x * 256 + threadIdx.x;       // 65536 threads x 4 elems
    const float4 v = *(const float4*)(x + (size_t)gid * 4);
    float am = fmaxf(fmaxf(fabsf(v.x), fabsf(v.y)), fmaxf(fabsf(v.z), fabsf(v.w)));
    am = fmaxf(am, __shfl_xor(am, 1));
    am = fmaxf(am, __shfl_xor(am, 2));
    am = fmaxf(am, __shfl_xor(am, 4));              // 8-lane group = one 32-block
    float scale, inv;
    mx_block_scale(am, scale, inv);
    ushort4 q;
    q.x = (unsigned short)bf16_trunc(mx_qd(v.x, scale, inv));
    q.y = (unsigned short)bf16_trunc(mx_qd(v.y, scale, inv));
    q.z = (unsigned short)bf16_trunc(mx_qd(v.z, scale, inv));
    q.w = (unsigned short)bf16_trunc(mx_qd(v.w, scale, inv));
    *(ushort4*)(x_dq + (size_t)gid * 4) = q;
}

// ---------------- kernel 2: barrier-free fused W-quant GEMM ----------------
// One wave owns 16 N-rows and one K-chunk of 512. B fragment loaded straight
// from global (lane n=lane&15, k=quad*8+j -> two float4s; 4 lanes of one n
// cover one contiguous 32-elem MXFP block). 4 MFMAs cover all 64 M rows.
// No LDS, no __syncthreads -> free software pipelining.
__global__ __launch_bounds__(256) void gemm_kernel(const unsigned short* __restrict__ x_dq,
                                                   const float* __restrict__ wgt,
                                                   float* __restrict__ partial) {
    const int lane  = threadIdx.x & 63;
    const int wid   = threadIdx.x >> 6;
    const int w     = blockIdx.x * 4 + wid;         // 0..5503
    const int nch   = w % NCHUNKS;
    const int split = w / NCHUNKS;
    const int nlo   = lane & 15;
    const int kq    = lane >> 4;                    // quad 0..3
    const int kbase = split * KCHUNK + kq * 8;

    const float*          wp = wgt  + (size_t)(nch * 16 + nlo) * DIN + kbase;
    const unsigned short* xp = x_dq + (size_t)nlo * DIN + kbase;

    f32x4 acc0 = {0.f,0.f,0.f,0.f};
    f32x4 acc1 = {0.f,0.f,0.f,0.f};
    f32x4 acc2 = {0.f,0.f,0.f,0.f};
    f32x4 acc3 = {0.f,0.f,0.f,0.f};

    float4 w0 = *(const float4*)(wp);
    float4 w1 = *(const float4*)(wp + 4);

    for (int kk = 0; kk < KCHUNK; kk += 32) {
        float4 c0 = w0, c1 = w1;
        if (kk + 32 < KCHUNK) {                     // prefetch next W pair
            w0 = *(const float4*)(wp + kk + 32);
            w1 = *(const float4*)(wp + kk + 36);
        }
        // A fragments for the 4 M-chunks (L1/L2-resident, 512 KB total)
        bf16x8 a0 = *(const bf16x8*)(xp + kk);
        bf16x8 a1 = *(const bf16x8*)(xp + 16 * DIN + kk);
        bf16x8 a2 = *(const bf16x8*)(xp + 32 * DIN + kk);
        bf16x8 a3 = *(const bf16x8*)(xp + 48 * DIN + kk);

        // 32-block absmax: in-lane 8, then the 4 lanes sharing this n-row
        float am = fmaxf(fmaxf(fmaxf(fabsf(c0.x), fabsf(c0.y)), fmaxf(fabsf(c0.z), fabsf(c0.w))),
                         fmaxf(fmaxf(fabsf(c1.x), fabsf(c1.y)), fmaxf(fabsf(c1.z), fabsf(c1.w))));
        am = fmaxf(am, __shfl_xor(am, 16));
        am = fmaxf(am, __shfl_xor(am, 32));
        float scale, inv;
        mx_block_scale(am, scale, inv);

        bf16x8 bf;
        bf[0] = bf16_trunc(mx_qd(c0.x, scale, inv));
        bf[1] = bf16_trunc(mx_qd(c0.y, scale, inv));
        bf[2] = bf16_trunc(mx_qd(c0.z, scale, inv));
        bf[3] = bf16_trunc(mx_qd(c0.w, scale, inv));
        bf[4] = bf16_trunc(mx_qd(c1.x, scale, inv));
        bf[5] = bf16_trunc(mx_qd(c1.y, scale, inv));
        bf[6] = bf16_trunc(mx_qd(c1.z, scale, inv));
        bf[7] = bf16_trunc(mx_qd(c1.w, scale, inv));

        acc0 = __builtin_amdgcn_mfma_f32_16x16x32_bf16(a0, bf, acc0, 0, 0, 0);
        acc1 = __builtin_amdgcn_mfma_f32_16x16x32_bf16(a1, bf, acc1, 0, 0, 0);
        acc2 = __builtin_amdgcn_mfma_f32_16x16x32_bf16(a2, bf, acc2, 0, 0, 0);
        acc3 = __builtin_amdgcn_mfma_f32_16x16x32_bf16(a3, bf, acc3, 0, 0, 0);
    }

    // C/D map: col(n)=lane&15, row(m)=quad*4+reg (verified round 1, absmax 0)
    float* pp = partial + (size_t)split * (TM * DOUT) + (size_t)(nch * 16 + nlo);
    const int mrow = kq * 4;
    #pragma unroll
    for (int r = 0; r < 4; ++r) {
        pp[(size_t)(mrow + r) * DOUT]      = acc0[r];
        pp[(size_t)(16 + mrow + r) * DOUT] = acc1[r];
        pp[(size_t)(32 + mrow + r) * DOUT] = acc2[r];
        pp[(size_t)(48 + mrow + r) * DOUT] = acc3[r];
    }
}

// ---------------- kernel 3: reduce K-splits + quantized bias ----------------
// gid = m*DOUT + n; DOUT % 64 == 0 so 32-lane halves align with bias blocks
__global__ __launch_bounds__(256) void reduce_bias_kernel(const float* __restrict__ partial,
                                                          const float* __restrict__ bias,
                                                          float* __restrict__ out) {
    int gid = blockIdx.x * 256 + threadIdx.x;       // 704512 threads
    float s = 0.f;
    #pragma unroll
    for (int i = 0; i < KSPLIT; ++i)
        s += partial[(size_t)i * (TM * DOUT) + gid];
    int n = gid % DOUT;
    float v = bias[n];
    float am = fabsf(v);
    am = fmaxf(am, __shfl_xor(am, 1));
    am = fmaxf(am, __shfl_xor(am, 2));
    am = fmaxf(am, __shfl_xor(am, 4));
    am = fmaxf(am, __shfl_xor(am, 8));
    am = fmaxf(am, __shfl_xor(am, 16));
    float scale, inv;
    mx_block_scale(am, scale, inv);
    out[gid] = s + mx_qd(v, scale, inv);
}

extern "C" void kernel_launch(void* const* d_in, const int* in_sizes, int n_in,
                              void* d_out, int out_size, void* d_ws, size_t ws_size,
                              hipStream_t stream) {
    const float* x    = (const float*)d_in[0];   // [64, 4096]
    const float* wgt  = (const float*)d_in[1];   // [11008, 4096]
    const float* bias = (const float*)d_in[2];   // [11008]
    float* out = (float*)d_out;                  // [64, 11008]

    unsigned short* x_dq    = (unsigned short*)d_ws;                 // 512 KB
    float*          partial = (float*)((char*)d_ws + 512 * 1024);    // 22.5 MB

    quant_x_kernel<<<256, 256, 0, stream>>>(x, x_dq);
    gemm_kernel<<<NCHUNKS * KSPLIT / 4, 256, 0, stream>>>(x_dq, wgt, partial);
    reduce_bias_kernel<<<TM * DOUT / 256, 256, 0, stream>>>(partial, bias, out);
}

// Round 3
// 274.374 us; speedup vs baseline: 1.0586x; 1.0586x over previous
//
#include <hip/hip_runtime.h>
#include <hip/hip_bf16.h>

#define DIN    4096
#define DOUT   11008
#define TM     64
#define KSPLIT 4
#define KCHUNK (DIN / KSPLIT)     // 1024
#define NCHUNKS (DOUT / 16)       // 688

typedef __attribute__((ext_vector_type(8))) short  bf16x8;
typedef __attribute__((ext_vector_type(4))) float  f32x4;

// floor(log2(safe_amax)) - 2, clipped; scale and 1/scale are powers of 2 (exact)
__device__ inline void mx_block_scale(float amax, float& scale, float& inv_scale) {
    float safe = amax > 0.0f ? amax : 1.0f;
    int e  = (int)((__float_as_uint(safe) >> 23) & 255) - 127; // floor(log2), normals
    int se = e - 2;
    if (se < -127) se = -127;       // E8M0_MIN clip (upper clip unreachable)
    scale     = ldexpf(1.0f, se);
    inv_scale = ldexpf(1.0f, -se);
}

// E2M1 quant-dequant of one element given the block scale (exact vs jnp ref)
__device__ inline float mx_qd(float v, float scale, float inv_scale) {
    float a = fabsf(v) * inv_scale;  // exact pow2 mult
    a = fminf(a, 6.0f);              // FP4_MAX saturate
    float step  = (a < 2.0f) ? 0.5f : (a < 4.0f) ? 1.0f : 2.0f;
    float rstep = (a < 2.0f) ? 2.0f : (a < 4.0f) ? 1.0f : 0.5f;
    float q = rintf(a * rstep) * step;   // round-half-even = jnp.round
    return copysignf(q * scale, v);
}

__device__ inline short bf16_trunc(float f) {
    // dequantized values have <=2 mantissa bits -> truncation exact
    return (short)(__float_as_uint(f) >> 16);
}

__device__ inline float blk_absmax8(const float4& a, const float4& b) {
    return fmaxf(fmaxf(fmaxf(fabsf(a.x), fabsf(a.y)), fmaxf(fabsf(a.z), fabsf(a.w))),
                 fmaxf(fmaxf(fabsf(b.x), fabsf(b.y)), fmaxf(fabsf(b.z), fabsf(b.w))));
}

// ---------------- kernel 1: quantize x -> bf16 in ws (exact) ----------------
__global__ __launch_bounds__(256) void quant_x_kernel(const float* __restrict__ x,
                                                      unsigned short* __restrict__ x_dq) {
    int gid = blockIdx.x * 256 + threadIdx.x;       // 65536 threads x 4 elems
    const float4 v = *(const float4*)(x + (size_t)gid * 4);
    float am = fmaxf(fmaxf(fabsf(v.x), fabsf(v.y)), fmaxf(fabsf(v.z), fabsf(v.w)));
    am = fmaxf(am, __shfl_xor(am, 1));
    am = fmaxf(am, __shfl_xor(am, 2));
    am = fmaxf(am, __shfl_xor(am, 4));              // 8-lane group = one 32-block
    float scale, inv;
    mx_block_scale(am, scale, inv);
    ushort4 q;
    q.x = (unsigned short)bf16_trunc(mx_qd(v.x, scale, inv));
    q.y = (unsigned short)bf16_trunc(mx_qd(v.y, scale, inv));
    q.z = (unsigned short)bf16_trunc(mx_qd(v.z, scale, inv));
    q.w = (unsigned short)bf16_trunc(mx_qd(v.w, scale, inv));
    *(ushort4*)(x_dq + (size_t)gid * 4) = q;
}

// ---------------- kernel 2: barrier-free fused W-quant GEMM ----------------
// One wave owns 16 N-rows and one K-chunk of 1024. B fragment loaded straight
// from global (n=lane&15, k=quad*8+j -> two float4s; the 4 lanes of one n-row
// cover one contiguous 32-elem MXFP block). 4 MFMAs cover all 64 M rows.
// 2-deep pipeline: W(k+2) in flight | scale(k+1) computed | quant+MFMA(k).
// The shfl (ds_permute) latency of scale(k+1) overlaps quant+MFMA(k).
__global__ __launch_bounds__(256) void gemm_kernel(const unsigned short* __restrict__ x_dq,
                                                   const float* __restrict__ wgt,
                                                   float* __restrict__ partial) {
    const int lane  = threadIdx.x & 63;
    const int wid   = threadIdx.x >> 6;
    const int w     = blockIdx.x * 4 + wid;         // 0..2751
    const int nch   = w % NCHUNKS;
    const int split = w / NCHUNKS;
    const int nlo   = lane & 15;
    const int kq    = lane >> 4;                    // quad 0..3
    const int kbase = split * KCHUNK + kq * 8;

    const float*          wp = wgt  + (size_t)(nch * 16 + nlo) * DIN + kbase;
    const unsigned short* xp = x_dq + (size_t)nlo * DIN + kbase;

    f32x4 acc0 = {0.f,0.f,0.f,0.f};
    f32x4 acc1 = {0.f,0.f,0.f,0.f};
    f32x4 acc2 = {0.f,0.f,0.f,0.f};
    f32x4 acc3 = {0.f,0.f,0.f,0.f};

    // pipeline prologue: wa = W(k), wb = W(k+32) in flight, scale for wa ready
    float4 wa0 = *(const float4*)(wp);
    float4 wa1 = *(const float4*)(wp + 4);
    float4 wb0 = *(const float4*)(wp + 32);
    float4 wb1 = *(const float4*)(wp + 36);
    float am = blk_absmax8(wa0, wa1);
    am = fmaxf(am, __shfl_xor(am, 16));
    am = fmaxf(am, __shfl_xor(am, 32));
    float scale, inv;
    mx_block_scale(am, scale, inv);

    #pragma unroll 4
    for (int kk = 0; kk < KCHUNK; kk += 32) {
        // issue W(k+64); clamp keeps the last iterations in-bounds (dup load)
        const int kpre = (kk + 64 < KCHUNK) ? kk + 64 : KCHUNK - 32;
        float4 wc0 = *(const float4*)(wp + kpre);
        float4 wc1 = *(const float4*)(wp + kpre + 4);

        // A fragments (x_dq is 512 KB, L1/L2-resident)
        bf16x8 a0 = *(const bf16x8*)(xp + kk);
        bf16x8 a1 = *(const bf16x8*)(xp + 16 * DIN + kk);
        bf16x8 a2 = *(const bf16x8*)(xp + 32 * DIN + kk);
        bf16x8 a3 = *(const bf16x8*)(xp + 48 * DIN + kk);

        // quantize current tile with the pre-computed scale
        bf16x8 bf;
        bf[0] = bf16_trunc(mx_qd(wa0.x, scale, inv));
        bf[1] = bf16_trunc(mx_qd(wa0.y, scale, inv));
        bf[2] = bf16_trunc(mx_qd(wa0.z, scale, inv));
        bf[3] = bf16_trunc(mx_qd(wa0.w, scale, inv));
        bf[4] = bf16_trunc(mx_qd(wa1.x, scale, inv));
        bf[5] = bf16_trunc(mx_qd(wa1.y, scale, inv));
        bf[6] = bf16_trunc(mx_qd(wa1.z, scale, inv));
        bf[7] = bf16_trunc(mx_qd(wa1.w, scale, inv));

        acc0 = __builtin_amdgcn_mfma_f32_16x16x32_bf16(a0, bf, acc0, 0, 0, 0);
        acc1 = __builtin_amdgcn_mfma_f32_16x16x32_bf16(a1, bf, acc1, 0, 0, 0);
        acc2 = __builtin_amdgcn_mfma_f32_16x16x32_bf16(a2, bf, acc2, 0, 0, 0);
        acc3 = __builtin_amdgcn_mfma_f32_16x16x32_bf16(a3, bf, acc3, 0, 0, 0);

        // scale for the NEXT tile (wb arrived long ago); shfl latency overlaps
        // the MFMAs just issued
        float amn = blk_absmax8(wb0, wb1);
        amn = fmaxf(amn, __shfl_xor(amn, 16));
        amn = fmaxf(amn, __shfl_xor(amn, 32));
        mx_block_scale(amn, scale, inv);

        wa0 = wb0; wa1 = wb1;
        wb0 = wc0; wb1 = wc1;
    }

    // C/D map: col(n)=lane&15, row(m)=quad*4+reg (verified: absmax 0)
    float* pp = partial + (size_t)split * (TM * DOUT) + (size_t)(nch * 16 + nlo);
    const int mrow = kq * 4;
    #pragma unroll
    for (int r = 0; r < 4; ++r) {
        pp[(size_t)(mrow + r) * DOUT]      = acc0[r];
        pp[(size_t)(16 + mrow + r) * DOUT] = acc1[r];
        pp[(size_t)(32 + mrow + r) * DOUT] = acc2[r];
        pp[(size_t)(48 + mrow + r) * DOUT] = acc3[r];
    }
}

// ---------------- kernel 3: reduce K-splits + quantized bias ----------------
__global__ __launch_bounds__(256) void reduce_bias_kernel(const float* __restrict__ partial,
                                                          const float* __restrict__ bias,
                                                          float* __restrict__ out) {
    int gid = blockIdx.x * 256 + threadIdx.x;       // 704512 threads
    float s = 0.f;
    #pragma unroll
    for (int i = 0; i < KSPLIT; ++i)
        s += partial[(size_t)i * (TM * DOUT) + gid];
    int n = gid % DOUT;
    float v = bias[n];
    float am = fabsf(v);
    am = fmaxf(am, __shfl_xor(am, 1));
    am = fmaxf(am, __shfl_xor(am, 2));
    am = fmaxf(am, __shfl_xor(am, 4));
    am = fmaxf(am, __shfl_xor(am, 8));
    am = fmaxf(am, __shfl_xor(am, 16));
    float scale, inv;
    mx_block_scale(am, scale, inv);
    out[gid] = s + mx_qd(v, scale, inv);
}

extern "C" void kernel_launch(void* const* d_in, const int* in_sizes, int n_in,
                              void* d_out, int out_size, void* d_ws, size_t ws_size,
                              hipStream_t stream) {
    const float* x    = (const float*)d_in[0];   // [64, 4096]
    const float* wgt  = (const float*)d_in[1];   // [11008, 4096]
    const float* bias = (const float*)d_in[2];   // [11008]
    float* out = (float*)d_out;                  // [64, 11008]

    unsigned short* x_dq    = (unsigned short*)d_ws;                 // 512 KB
    float*          partial = (float*)((char*)d_ws + 512 * 1024);    // 11.25 MB

    quant_x_kernel<<<256, 256, 0, stream>>>(x, x_dq);
    gemm_kernel<<<NCHUNKS * KSPLIT / 4, 256, 0, stream>>>(x_dq, wgt, partial);
    reduce_bias_kernel<<<TM * DOUT / 256, 256, 0, stream>>>(partial, bias, out);
}